// Round 1
// baseline (2338.433 us; speedup 1.0000x reference)
//
#include <hip/hip_runtime.h>
#include <math.h>

#define KNN 30
#define QT 16          // queries per block
#define NTH 256
#define CAP 192        // candidate capacity per query
#define NBUCKET 512
#define HSTRIDE 513    // +1 pad: bank = (q + bucket) & 31
#define STARGET 14u    // sampled-cum target (1/4 sampling)
#define SIGMA_N 0.8f
#define THRESHV 1e-3f

__global__ void prep_pack(const float* __restrict__ src, float4* __restrict__ dst, int M) {
    int j = blockIdx.x * 256 + threadIdx.x;
    if (j < M) {
        float x = src[3*j+0], y = src[3*j+1], z = src[3*j+2];
        dst[j] = make_float4(x, y, z, 0.5f*(x*x + y*y + z*z));
    }
}

template<bool PACKED>
__device__ __forceinline__ float4 fetch_pt(const float4* __restrict__ sp,
                                           const float* __restrict__ sv, int j) {
    if (PACKED) return sp[j];
    float x = sv[3*j+0], y = sv[3*j+1], z = sv[3*j+2];
    return make_float4(x, y, z, 0.5f*(x*x + y*y + z*z));
}

template<bool PACKED>
__global__ __launch_bounds__(NTH)
void rimls_fused(const float* __restrict__ qpts,
                 const float* __restrict__ sverts,
                 const float* __restrict__ snorms,
                 const float4* __restrict__ spack,
                 float* __restrict__ out,
                 int N, int M)
{
    // regionA: phase1-2 histogram -> phase3-4 candidate lists -> phase6 neighbor cache
    __shared__ unsigned int regionA[QT * HSTRIDE];          // 32832 B
    __shared__ float4 qbuf[QT];
    __shared__ float sel_d[QT * KNN];
    __shared__ int   sel_i[QT * KNN];
    __shared__ unsigned int cnt[QT];
    __shared__ unsigned int Tbits[QT];
    __shared__ int retryq[QT];
    __shared__ int retryAny;
    __shared__ float h2v[QT], c8v[QT];

    const int t = threadIdx.x;
    const int q = t & (QT - 1);   // phases 1-3: query owned by this lane
    const int c = t >> 4;         // source chunk 0..15

    if (t < QT) {
        int gq = blockIdx.x * QT + t;
        if (gq >= N) gq = N - 1;
        float x = qpts[3*gq+0], y = qpts[3*gq+1], z = qpts[3*gq+2];
        qbuf[t] = make_float4(x, y, z, 0.5f*(x*x + y*y + z*z));
        cnt[t] = 0u; retryq[t] = 0;
    }
    if (t == 0) retryAny = 0;
    for (int i = t; i < QT * HSTRIDE; i += NTH) regionA[i] = 0u;
    for (int i = t; i < QT * KNN; i += NTH) { sel_d[i] = 0.0f; sel_i[i] = 0; }
    __syncthreads();

    const float qx = qbuf[q].x, qy = qbuf[q].y, qz = qbuf[q].z, q2h = qbuf[q].w;
    unsigned int* hist = regionA + q * HSTRIDE;

    // ---- phase 1: sampled (1/4) histogram of d2/2 top-9-bits ----
    {
        const int n1 = M >> 6;
        #pragma unroll 4
        for (int i = 0; i < n1; ++i) {
            int j = (c + (i << 4)) << 2;          // every 4th point
            float4 s = fetch_pt<PACKED>(spack, sverts, j);
            float v = fmaf(-qx, s.x, fmaf(-qy, s.y, fmaf(-qz, s.z, s.w + q2h)));
            v = fmaxf(v, 0.0f);
            unsigned int b = __float_as_uint(v) >> 22;
            atomicAdd(&hist[b], 1u);
        }
    }
    __syncthreads();

    // ---- phase 2: per-query threshold (bucket upper edge) ----
    if (t < QT) {
        const unsigned int* h_ = regionA + t * HSTRIDE;
        unsigned int cum = 0; int b = 0;
        for (; b < NBUCKET; ++b) { cum += h_[b]; if (cum >= STARGET) break; }
        if (b >= NBUCKET) b = NBUCKET - 1;
        unsigned int tb = (unsigned int)(b + 1) << 22;
        if (tb > (510u << 22)) tb = 510u << 22;   // 510<<22 == +inf
        Tbits[t] = tb;
    }
    __syncthreads();

    float* cand_d = (float*)regionA;              // [QT*CAP] (aliases dead histogram)
    int*   cand_i = (int*)(regionA + QT * CAP);   // [QT*CAP]

    // ---- phase 3: collect candidates below threshold, with bounded retry ----
    const int n3 = M >> 4;
    for (int round = 0; round < 10; ++round) {
        bool active = (round == 0) || (retryq[q] != 0);
        if (active) {
            const float Tq = __uint_as_float(Tbits[q]);
            #pragma unroll 4
            for (int i = 0; i < n3; ++i) {
                int j = c + (i << 4);
                float4 s = fetch_pt<PACKED>(spack, sverts, j);
                float v = fmaf(-qx, s.x, fmaf(-qy, s.y, fmaf(-qz, s.z, s.w + q2h)));
                v = fmaxf(v, 0.0f);
                if (v < Tq) {
                    unsigned int pos = atomicAdd(&cnt[q], 1u);
                    if (pos < (unsigned)CAP) { cand_d[q*CAP + pos] = v; cand_i[q*CAP + pos] = j; }
                }
            }
        }
        __syncthreads();
        if (t == 0) retryAny = 0;
        __syncthreads();
        if (t < QT) {
            unsigned int cc = cnt[t];
            unsigned int tb = Tbits[t];
            int bad = 0;
            if (cc < (unsigned)KNN) {
                if (tb < (510u << 22)) {
                    tb += (2u << 22);
                    if (tb > (510u << 22)) tb = 510u << 22;
                    bad = 1;
                }
            } else if (cc > (unsigned)CAP && round < 5) {
                tb -= (1u << 22); bad = 1;
            }
            if (bad) { Tbits[t] = tb; cnt[t] = 0u; retryq[t] = 1; atomicExch(&retryAny, 1); }
            else retryq[t] = 0;
        }
        __syncthreads();
        if (retryAny == 0) break;
    }

    // ---- phase 4: exact rank-select of 30 smallest (remap: 16 lanes per query) ----
    const int q4 = t >> 4;
    const int s4 = t & 15;
    {
        unsigned int cc = cnt[q4];
        int C = (int)(cc < (unsigned)CAP ? cc : (unsigned)CAP);
        const float* cd = cand_d + q4 * CAP;
        const int*   ci = cand_i + q4 * CAP;
        for (int a = s4; a < C; a += 16) {
            float da = cd[a]; int ia = ci[a];
            int rank = 0;
            for (int b = 0; b < C; ++b) {
                float db = cd[b]; int ib = ci[b];
                rank += (db < da || (db == da && ib < ia)) ? 1 : 0;
            }
            if (rank < KNN) { sel_d[q4*KNN + rank] = da; sel_i[q4*KNN + rank] = ia; }
        }
    }
    __syncthreads();

    // ---- phase 5: bandwidth h = mean neighbor distance + eps ----
    if (t < QT) {
        float sum = 0.0f;
        for (int k = 0; k < KNN; ++k)
            sum += sqrtf(fmaxf(2.0f * sel_d[t*KNN + k], 0.0f));
        float h = sum / (float)KNN + 1e-8f;
        float h2 = h * h;
        h2v[t] = h2; c8v[t] = -8.0f / h2;
    }
    __syncthreads();

    // ---- phase 6a: per-neighbor statics into LDS (reuse regionA) ----
    float* nb = (float*)regionA;  // [QT][KNN][9]: px py pz nx ny nz fx phi gcoef
    {
        const float qx4 = qbuf[q4].x, qy4 = qbuf[q4].y, qz4 = qbuf[q4].z;
        const float h2 = h2v[q4], c8 = c8v[q4];
        for (int k = s4; k < KNN; k += 16) {
            int j = sel_i[q4*KNN + k];
            float4 s = fetch_pt<PACKED>(spack, sverts, j);
            float px = qx4 - s.x, py = qy4 - s.y, pz = qz4 - s.z;
            float nx = snorms[3*j+0], ny = snorms[3*j+1], nz = snorms[3*j+2];
            float nrm = sqrtf(nx*nx + ny*ny + nz*nz);
            float inv = 1.0f / fmaxf(nrm, 1e-8f);
            nx *= inv; ny *= inv; nz *= inv;
            float fx = px*nx + py*ny + pz*nz;
            float r2 = px*px + py*py + pz*pz;
            float tt = fmaxf(1.0f - r2 / h2, 0.0f);
            float t2 = tt * tt;
            float* p = nb + (q4*KNN + k) * 9;
            p[0]=px; p[1]=py; p[2]=pz; p[3]=nx; p[4]=ny; p[5]=nz;
            p[6]=fx; p[7]=t2*t2; p[8]=c8*(t2*tt);
        }
    }
    __syncthreads();

    // ---- phase 6b: robust refit iterations (16-lane-group reductions) ----
    {
        const float inv_sn2 = 1.0f / (SIGMA_N * SIGMA_N);
        float f = 0.0f, gx = 0.0f, gy = 0.0f, gz = 0.0f;
        bool done = false;
        for (int it = 0; it < 3; ++it) {
            if (done) break;
            float sw=0, swf=0, sgx=0, sgy=0, sgz=0, sfx=0, sfy=0, sfz=0, snx=0, sny=0, snz=0;
            for (int k = s4; k < KNN; k += 16) {
                const float* p = nb + (q4*KNN + k) * 9;
                float px=p[0], py=p[1], pz=p[2], nx=p[3], ny=p[4], nz=p[5];
                float fx=p[6], phi=p[7], gco=p[8];
                float alpha = 1.0f;
                if (it > 0) {
                    float dx = nx - gx, dy = ny - gy, dz = nz - gz;
                    alpha = expf(-(dx*dx + dy*dy + dz*dz) * inv_sn2);
                }
                float w = alpha * phi;
                float g = alpha * gco;
                float gf = g * fx;
                sw += w; swf += w * fx;
                sgx += g*px;  sgy += g*py;  sgz += g*pz;
                sfx += gf*px; sfy += gf*py; sfz += gf*pz;
                snx += w*nx;  sny += w*ny;  snz += w*nz;
            }
            #pragma unroll
            for (int m = 1; m < 16; m <<= 1) {
                sw  += __shfl_xor(sw, m);  swf += __shfl_xor(swf, m);
                sgx += __shfl_xor(sgx, m); sgy += __shfl_xor(sgy, m); sgz += __shfl_xor(sgz, m);
                sfx += __shfl_xor(sfx, m); sfy += __shfl_xor(sfy, m); sfz += __shfl_xor(sfz, m);
                snx += __shfl_xor(snx, m); sny += __shfl_xor(sny, m); snz += __shfl_xor(snz, m);
            }
            sw += 1e-8f;
            float fn  = swf / sw;
            float gnx = (sfx + snx - fn*sgx) / sw;
            float gny = (sfy + sny - fn*sgy) / sw;
            float gnz = (sfz + snz - fn*sgz) / sw;
            float delta = fabsf(fn - f);
            f = fn; gx = gnx; gy = gny; gz = gnz;
            done = (delta < THRESHV);
        }
        if (s4 == 0) {
            int gq = blockIdx.x * QT + q4;
            if (gq < N) {
                out[gq] = f;
                out[N + 3*gq + 0] = gx;
                out[N + 3*gq + 1] = gy;
                out[N + 3*gq + 2] = gz;
            }
        }
    }
}

extern "C" void kernel_launch(void* const* d_in, const int* in_sizes, int n_in,
                              void* d_out, int out_size, void* d_ws, size_t ws_size,
                              hipStream_t stream) {
    (void)n_in; (void)out_size;
    const float* qpts   = (const float*)d_in[0];
    const float* sverts = (const float*)d_in[1];
    const float* snorms = (const float*)d_in[2];
    float* out = (float*)d_out;
    int N = in_sizes[0] / 3;
    int M = in_sizes[1] / 3;
    int blocks = (N + QT - 1) / QT;

    if (ws_size >= (size_t)M * sizeof(float4)) {
        float4* spack = (float4*)d_ws;
        prep_pack<<<(M + 255) / 256, 256, 0, stream>>>(sverts, spack, M);
        rimls_fused<true><<<blocks, NTH, 0, stream>>>(qpts, sverts, snorms, spack, out, N, M);
    } else {
        rimls_fused<false><<<blocks, NTH, 0, stream>>>(qpts, sverts, snorms, nullptr, out, N, M);
    }
}

// Round 2
// 1509.572 us; speedup vs baseline: 1.5491x; 1.5491x over previous
//
#include <hip/hip_runtime.h>
#include <math.h>

#define KNN 30
#define QT 32          // queries per block
#define NTH 256
#define CAP 160        // candidate capacity per query
#define CAPS 161       // padded stride (bank spread)
#define RSEL 20        // rank in the 1/4 sample -> E[full count] = 80
#define SIGMA_N 0.8f
#define THRESHV 1e-3f

__global__ void prep_pack(const float* __restrict__ src, float4* __restrict__ dst, int M) {
    int j = blockIdx.x * 256 + threadIdx.x;
    if (j < M) {
        float x = src[3*j+0], y = src[3*j+1], z = src[3*j+2];
        dst[j] = make_float4(x, y, z, 0.5f*(x*x + y*y + z*z));
    }
}

template<bool PACKED>
__device__ __forceinline__ float4 fetch_pt(const float4* __restrict__ sp,
                                           const float* __restrict__ sv, int j) {
    if (PACKED) return sp[j];
    float x = sv[3*j+0], y = sv[3*j+1], z = sv[3*j+2];
    return make_float4(x, y, z, 0.5f*(x*x + y*y + z*z));
}

__device__ __forceinline__ void ins4(unsigned int k, unsigned int &m0, unsigned int &m1,
                                     unsigned int &m2, unsigned int &m3) {
    if (k < m3) {
        if (k < m2) {
            m3 = m2;
            if (k < m1) { m2 = m1; if (k < m0) { m1 = m0; m0 = k; } else m1 = k; }
            else m2 = k;
        } else m3 = k;
    }
}

template<bool PACKED>
__global__ __launch_bounds__(NTH)
void rimls_fused(const float* __restrict__ qpts,
                 const float* __restrict__ sverts,
                 const float* __restrict__ snorms,
                 const float4* __restrict__ spack,
                 float* __restrict__ out,
                 int N, int M)
{
    __shared__ unsigned int cand[QT * CAPS];   // 20608 B; phase-1 merge buf aliases front
    __shared__ unsigned int selk[QT * KNN];    // 3840 B
    __shared__ float4 qbuf[QT];
    __shared__ unsigned int cnt[QT];
    __shared__ unsigned int T16[QT];
    __shared__ int retryq[QT];

    const int t  = threadIdx.x;
    const int qg = t >> 4;        // 0..15 (16 consecutive lanes per group)
    const int c  = t & 15;        // chunk within group
    const int qa = qg, qb = qg + 16;  // the 2 queries this thread owns

    if (t < QT) {
        int gq = blockIdx.x * QT + t; if (gq >= N) gq = N - 1;
        float x = qpts[3*gq+0], y = qpts[3*gq+1], z = qpts[3*gq+2];
        qbuf[t] = make_float4(x, y, z, 0.5f*(x*x + y*y + z*z));
    }
    for (int i = t; i < QT * KNN; i += NTH) selk[i] = 0u;
    __syncthreads();

    const float ax = qbuf[qa].x, ay = qbuf[qa].y, az = qbuf[qa].z, aw = qbuf[qa].w;
    const float bx = qbuf[qb].x, by = qbuf[qb].y, bz = qbuf[qb].z, bw = qbuf[qb].w;

    // ---- phase 1: 1/4 sample, per-thread top-4 packed keys (no atomics) ----
    unsigned int a0=~0u,a1=~0u,a2=~0u,a3=~0u, b0=~0u,b1=~0u,b2=~0u,b3=~0u;
    {
        const int n1 = M >> 6;
        #pragma unroll 2
        for (int i = 0; i < n1; ++i) {
            int j = (c + (i << 4)) << 2;
            float4 s = fetch_pt<PACKED>(spack, sverts, j);
            float va = fmaxf(fmaf(-ax, s.x, fmaf(-ay, s.y, fmaf(-az, s.z, s.w + aw))), 0.0f);
            float vb = fmaxf(fmaf(-bx, s.x, fmaf(-by, s.y, fmaf(-bz, s.z, s.w + bw))), 0.0f);
            unsigned int ka = (__float_as_uint(va) & 0xFFFF0000u) | (unsigned int)j;
            unsigned int kb = (__float_as_uint(vb) & 0xFFFF0000u) | (unsigned int)j;
            ins4(ka, a0, a1, a2, a3);
            ins4(kb, b0, b1, b2, b3);
        }
    }
    {   // merge: 16 threads x 4 keys per query into cand area
        unsigned int* mb = cand;
        mb[qa*64 + c*4 + 0] = a0; mb[qa*64 + c*4 + 1] = a1;
        mb[qa*64 + c*4 + 2] = a2; mb[qa*64 + c*4 + 3] = a3;
        mb[qb*64 + c*4 + 0] = b0; mb[qb*64 + c*4 + 1] = b1;
        mb[qb*64 + c*4 + 2] = b2; mb[qb*64 + c*4 + 3] = b3;
    }
    __syncthreads();
    if (t < QT) {
        const unsigned int* m_ = cand + t * 64;
        unsigned int kth = 0xFFFFFFFFu;
        for (int a = 0; a < 64; ++a) {
            unsigned int ka = m_[a]; int r = 0;
            for (int b = 0; b < 64; ++b) r += (m_[b] < ka) ? 1 : 0;
            if (r == RSEL - 1) kth = ka;
        }
        unsigned int tb = (kth >> 16) + 1u;
        if (tb > 0x7F00u) tb = 0x7F00u;
        T16[t] = tb; cnt[t] = 0u; retryq[t] = 1;
    }
    __syncthreads();

    // ---- phase 2: full-scan candidate collection with bounded retry ----
    const int n3 = M >> 4;
    for (int round = 0; round < 8; ++round) {
        bool aa = retryq[qa] != 0, ab = retryq[qb] != 0;
        if (aa || ab) {
            float Ta = aa ? __uint_as_float(T16[qa] << 16) : 0.0f;
            float Tb = ab ? __uint_as_float(T16[qb] << 16) : 0.0f;
            #pragma unroll 4
            for (int i = 0; i < n3; ++i) {
                int j = c + (i << 4);
                float4 s = fetch_pt<PACKED>(spack, sverts, j);
                float va = fmaxf(fmaf(-ax, s.x, fmaf(-ay, s.y, fmaf(-az, s.z, s.w + aw))), 0.0f);
                float vb = fmaxf(fmaf(-bx, s.x, fmaf(-by, s.y, fmaf(-bz, s.z, s.w + bw))), 0.0f);
                if (va < Ta) {
                    unsigned int pos = atomicAdd(&cnt[qa], 1u);
                    if (pos < (unsigned)CAP)
                        cand[qa*CAPS + pos] = (__float_as_uint(va) & 0xFFFF0000u) | (unsigned int)j;
                }
                if (vb < Tb) {
                    unsigned int pos = atomicAdd(&cnt[qb], 1u);
                    if (pos < (unsigned)CAP)
                        cand[qb*CAPS + pos] = (__float_as_uint(vb) & 0xFFFF0000u) | (unsigned int)j;
                }
            }
        }
        __syncthreads();
        int bad = 0;
        if (t < QT && retryq[t]) {
            unsigned int cc = cnt[t], tb = T16[t];
            if (cc < (unsigned)KNN) {
                if (tb < 0x7F00u) {
                    tb += (1u << 7);
                    if (tb > 0x7F00u) tb = 0x7F00u;
                    bad = 1;
                }
            } else if (cc > (unsigned)CAP && round < 4 && tb > (1u << 6)) {
                tb -= (1u << 6); bad = 1;
            }
            if (bad) { T16[t] = tb; cnt[t] = 0u; }
            else retryq[t] = 0;
        }
        if (!__syncthreads_or(bad)) break;
    }

    // ---- phase 3: exact rank-select of 30 smallest keys (8 lanes/query) ----
    const int qs = t >> 3, s8 = t & 7;
    {
        unsigned int cc = cnt[qs];
        int C = (int)(cc < (unsigned)CAP ? cc : (unsigned)CAP);
        const unsigned int* cd = cand + qs * CAPS;
        for (int a = s8; a < C; a += 8) {
            unsigned int ka = cd[a]; int r = 0;
            for (int b = 0; b < C; ++b) r += (cd[b] < ka) ? 1 : 0;
            if (r < KNN) selk[qs*KNN + r] = ka;
        }
    }
    __syncthreads();

    // ---- phase 4: epilogue, 8 lanes/query, neighbor statics in registers ----
    {
        const float qx = qbuf[qs].x, qy = qbuf[qs].y, qz = qbuf[qs].z;
        float px_[4], py_[4], pz_[4], nx_[4], ny_[4], nz_[4];
        float fx_[4], phi_[4], gco_[4], r2_[4];
        float dsum = 0.0f;
        #pragma unroll
        for (int u = 0; u < 4; ++u) {
            int k = s8 + 8*u;
            bool v = (k < KNN);
            int j = v ? (int)(selk[qs*KNN + k] & 0xFFFFu) : 0;
            float4 s = fetch_pt<PACKED>(spack, sverts, j);
            float px = qx - s.x, py = qy - s.y, pz = qz - s.z;
            float r2 = px*px + py*py + pz*pz;
            float nx = snorms[3*j+0], ny = snorms[3*j+1], nz = snorms[3*j+2];
            float nrm = sqrtf(nx*nx + ny*ny + nz*nz);
            float inv = 1.0f / fmaxf(nrm, 1e-8f);
            float m = v ? 1.0f : 0.0f;
            nx *= inv * m; ny *= inv * m; nz *= inv * m;
            px_[u] = px * m; py_[u] = py * m; pz_[u] = pz * m;
            nx_[u] = nx; ny_[u] = ny; nz_[u] = nz;
            r2_[u] = r2 * m;
            fx_[u] = px_[u]*nx + py_[u]*ny + pz_[u]*nz;
            dsum += v ? sqrtf(r2) : 0.0f;
            phi_[u] = m;   // placeholder, fixed after h known
        }
        dsum += __shfl_xor(dsum, 1);
        dsum += __shfl_xor(dsum, 2);
        dsum += __shfl_xor(dsum, 4);
        float h = dsum * (1.0f / (float)KNN) + 1e-8f;
        float h2 = h * h;
        float c8 = -8.0f / h2;
        #pragma unroll
        for (int u = 0; u < 4; ++u) {
            float tt = fmaxf(1.0f - r2_[u] / h2, 0.0f);
            float t2 = tt * tt;
            float valid = phi_[u];             // 1.0 or 0.0
            phi_[u] = t2 * t2 * valid;
            gco_[u] = c8 * t2 * tt * valid;
        }

        const float inv_sn2 = 1.0f / (SIGMA_N * SIGMA_N);
        float f = 0.0f, gx = 0.0f, gy = 0.0f, gz = 0.0f;
        bool done = false;
        for (int it = 0; it < 3; ++it) {
            if (done) break;
            float sw=0, swf=0, sgx=0, sgy=0, sgz=0, sfx=0, sfy=0, sfz=0, snx=0, sny=0, snz=0;
            #pragma unroll
            for (int u = 0; u < 4; ++u) {
                float alpha = 1.0f;
                if (it > 0) {
                    float dx = nx_[u]-gx, dy = ny_[u]-gy, dz = nz_[u]-gz;
                    alpha = expf(-(dx*dx + dy*dy + dz*dz) * inv_sn2);
                }
                float w = alpha * phi_[u];
                float g = alpha * gco_[u];
                float gf = g * fx_[u];
                sw  += w;          swf += w * fx_[u];
                sgx += g*px_[u];   sgy += g*py_[u];   sgz += g*pz_[u];
                sfx += gf*px_[u];  sfy += gf*py_[u];  sfz += gf*pz_[u];
                snx += w*nx_[u];   sny += w*ny_[u];   snz += w*nz_[u];
            }
            #pragma unroll
            for (int m = 1; m < 8; m <<= 1) {
                sw  += __shfl_xor(sw, m);  swf += __shfl_xor(swf, m);
                sgx += __shfl_xor(sgx, m); sgy += __shfl_xor(sgy, m); sgz += __shfl_xor(sgz, m);
                sfx += __shfl_xor(sfx, m); sfy += __shfl_xor(sfy, m); sfz += __shfl_xor(sfz, m);
                snx += __shfl_xor(snx, m); sny += __shfl_xor(sny, m); snz += __shfl_xor(snz, m);
            }
            sw += 1e-8f;
            float fn  = swf / sw;
            float gnx = (sfx + snx - fn*sgx) / sw;
            float gny = (sfy + sny - fn*sgy) / sw;
            float gnz = (sfz + snz - fn*sgz) / sw;
            float delta = fabsf(fn - f);
            f = fn; gx = gnx; gy = gny; gz = gnz;
            done = (delta < THRESHV);
        }
        if (s8 == 0) {
            int gq = blockIdx.x * QT + qs;
            if (gq < N) {
                out[gq] = f;
                out[N + 3*gq + 0] = gx;
                out[N + 3*gq + 1] = gy;
                out[N + 3*gq + 2] = gz;
            }
        }
    }
}

extern "C" void kernel_launch(void* const* d_in, const int* in_sizes, int n_in,
                              void* d_out, int out_size, void* d_ws, size_t ws_size,
                              hipStream_t stream) {
    (void)n_in; (void)out_size;
    const float* qpts   = (const float*)d_in[0];
    const float* sverts = (const float*)d_in[1];
    const float* snorms = (const float*)d_in[2];
    float* out = (float*)d_out;
    int N = in_sizes[0] / 3;
    int M = in_sizes[1] / 3;
    int blocks = (N + QT - 1) / QT;

    if (ws_size >= (size_t)M * sizeof(float4)) {
        float4* spack = (float4*)d_ws;
        prep_pack<<<(M + 255) / 256, 256, 0, stream>>>(sverts, spack, M);
        rimls_fused<true><<<blocks, NTH, 0, stream>>>(qpts, sverts, snorms, spack, out, N, M);
    } else {
        rimls_fused<false><<<blocks, NTH, 0, stream>>>(qpts, sverts, snorms, nullptr, out, N, M);
    }
}